// Round 8
// baseline (536.649 us; speedup 1.0000x reference)
//
#include <hip/hip_runtime.h>
#include <cstdint>
#include <cstddef>

typedef unsigned short u16;
typedef unsigned int u32;

__device__ __forceinline__ u16 f2b(float f) {
    u32 b = __float_as_uint(f);
    b += 0x7fffu + ((b >> 16) & 1u);   // RNE
    return (u16)(b >> 16);
}
__device__ __forceinline__ float b2f(u16 u) {
    return __uint_as_float(((u32)u) << 16);
}

// ================= u-precompute: u31 = W31@Wr3[0:64], u32 = W32@Wr3[64:128], c3 =================
__global__ void uprep(const float* __restrict__ W31, const float* __restrict__ W32,
                      const float* __restrict__ b31, const float* __restrict__ b32,
                      const float* __restrict__ Wr3, const float* __restrict__ br3,
                      float* __restrict__ u31, float* __restrict__ u32, float* __restrict__ c3) {
    __shared__ float s[64];
    int t = threadIdx.x;
    if (t < 128) {
        float a = 0.f, b = 0.f;
        for (int c = 0; c < 64; ++c) {
            a = fmaf(W31[t * 64 + c], Wr3[c], a);
            b = fmaf(W32[t * 64 + c], Wr3[64 + c], b);
        }
        u31[t] = a;
        u32[t] = b;
    }
    if (t < 64) s[t] = b31[t] * Wr3[t] + b32[t] * Wr3[64 + t];
    __syncthreads();
    if (t < 32) s[t] += s[t + 32];
    __syncthreads();
    if (t == 0) {
        float acc = 0.f;
        for (int i = 0; i < 32; ++i) acc += s[i];
        c3[0] = acc + br3[0];
    }
}

// ================= CSR build =================
__global__ void degcnt_all(const int* __restrict__ c1, const int* __restrict__ c2,
                           int* __restrict__ degc, int N, int E1, int E2) {
    int e = blockIdx.x * blockDim.x + threadIdx.x;
    if (e < E1) atomicAdd(&degc[c1[e]], 1);
    else if (e < E1 + E2) atomicAdd(&degc[N + c2[e - E1]], 1);
}

__global__ void dinv_fin(const int* __restrict__ degc, float* __restrict__ d1,
                         float* __restrict__ d2, int n) {
    int i = blockIdx.x * blockDim.x + threadIdx.x;
    if (i < n) {
        int a = degc[i], b = degc[n + i];
        d1[i] = a > 0 ? rsqrtf((float)a) : 0.f;
        d2[i] = b > 0 ? rsqrtf((float)b) : 0.f;
    }
}

__global__ void scan1(const int* __restrict__ deg, int* __restrict__ partial, int n) {
    __shared__ int s[256];
    int i = blockIdx.x * 256 + threadIdx.x;
    s[threadIdx.x] = (i < n) ? deg[i] : 0;
    __syncthreads();
    for (int off = 128; off > 0; off >>= 1) {
        if (threadIdx.x < off) s[threadIdx.x] += s[threadIdx.x + off];
        __syncthreads();
    }
    if (threadIdx.x == 0) partial[blockIdx.x] = s[0];
}

__global__ void scan2(int* __restrict__ partial, int nb, int* __restrict__ starts, int n) {
    __shared__ int s[512];
    int t = threadIdx.x;
    int v = (t < nb) ? partial[t] : 0;
    s[t] = v;
    __syncthreads();
    for (int off = 1; off < 512; off <<= 1) {
        int u = (t >= off) ? s[t - off] : 0;
        __syncthreads();
        s[t] += u;
        __syncthreads();
    }
    if (t < nb) partial[t] = s[t] - v;
    if (t == 511) starts[n] = s[511];
}

__global__ void scan3(const int* __restrict__ deg, const int* __restrict__ partial,
                      int* __restrict__ starts, int n) {
    __shared__ int s[256];
    int i = blockIdx.x * 256 + threadIdx.x;
    int v = (i < n) ? deg[i] : 0;
    s[threadIdx.x] = v;
    __syncthreads();
    for (int off = 1; off < 256; off <<= 1) {
        int u = (threadIdx.x >= off) ? s[threadIdx.x - off] : 0;
        __syncthreads();
        s[threadIdx.x] += u;
        __syncthreads();
    }
    if (i < n) starts[i] = partial[blockIdx.x] + s[threadIdx.x] - v;
}

// fill CSR slots for dests in [lo,hi) only — keeps the live write region L2-resident
// so lines are fully filled before writeback (kills the 8x partial-line amplification).
__global__ void csr_fill_pass(const int* __restrict__ ei1, const int* __restrict__ ei2,
                              const float* __restrict__ dinv1, const float* __restrict__ dinv2,
                              const int* __restrict__ starts, int* __restrict__ degc,
                              int2* __restrict__ csr, int N, int E1, int E2, int lo, int hi) {
    int e = blockIdx.x * blockDim.x + threadIdx.x;
    int c, base;
    const int* rows;
    const float* dinv;
    int idx;
    if (e < E1) { c = ei1[E1 + e]; base = 0; rows = ei1; dinv = dinv1; idx = e; }
    else if (e < E1 + E2) { int t = e - E1; c = ei2[E2 + t]; base = N; rows = ei2; dinv = dinv2; idx = t; }
    else return;
    if (c < lo || c >= hi) return;
    int r = rows[idx];
    int pos = starts[base + c] + atomicSub(&degc[base + c], 1) - 1;
    csr[pos] = make_int2(r, __float_as_int(dinv[r] * dinv[c]));
}

// ================= mm_in: R0 = relu(x@W_in + b_in); fused readout0 + outacc init =================
__global__ __launch_bounds__(256) void mm_in(const float* __restrict__ A, const float* __restrict__ W,
                                             const float* __restrict__ bias, float* __restrict__ C,
                                             const float* __restrict__ Wr0, const float* __restrict__ br0,
                                             const float* __restrict__ br1, const float* __restrict__ br2,
                                             const float* __restrict__ w0, const float* __restrict__ w1,
                                             const float* __restrict__ w2, const float* __restrict__ w3,
                                             const float* __restrict__ c3, float* __restrict__ outacc,
                                             int n) {
    __shared__ float As[64][68];
    __shared__ float Ws[64][68];
    const int tid = threadIdx.x;
    const int r0 = blockIdx.x * 64;

    for (int idx = tid; idx < 64 * 16; idx += 256) {
        int k = idx >> 4, cq = (idx & 15) * 4;
        *(float4*)&Ws[k][cq] = *(const float4*)&W[k * 64 + cq];
    }

    const int tr = (tid >> 4) * 4;
    const int tc = (tid & 15) * 4;
    float4 acc0 = {0,0,0,0}, acc1 = {0,0,0,0}, acc2 = {0,0,0,0}, acc3 = {0,0,0,0};

    __syncthreads();
#pragma unroll
    for (int it = 0; it < 4; ++it) {
        int r = (tid >> 4) + it * 16;
        int cq = (tid & 15) * 4;
        int gr = r0 + r;
        float4 v = {0,0,0,0};
        if (gr < n) v = *(const float4*)&A[(size_t)gr * 64 + cq];
        *(float4*)&As[r][cq] = v;
    }
    __syncthreads();
#pragma unroll
    for (int k = 0; k < 64; k += 4) {
        float4 a0 = *(const float4*)&As[tr + 0][k];
        float4 a1 = *(const float4*)&As[tr + 1][k];
        float4 a2 = *(const float4*)&As[tr + 2][k];
        float4 a3 = *(const float4*)&As[tr + 3][k];
        float4 b0 = *(const float4*)&Ws[k + 0][tc];
        float4 b1 = *(const float4*)&Ws[k + 1][tc];
        float4 b2 = *(const float4*)&Ws[k + 2][tc];
        float4 b3 = *(const float4*)&Ws[k + 3][tc];
#define DK(comp, B)                                                                   \
        acc0.x = fmaf(a0.comp, B.x, acc0.x); acc0.y = fmaf(a0.comp, B.y, acc0.y);     \
        acc0.z = fmaf(a0.comp, B.z, acc0.z); acc0.w = fmaf(a0.comp, B.w, acc0.w);     \
        acc1.x = fmaf(a1.comp, B.x, acc1.x); acc1.y = fmaf(a1.comp, B.y, acc1.y);     \
        acc1.z = fmaf(a1.comp, B.z, acc1.z); acc1.w = fmaf(a1.comp, B.w, acc1.w);     \
        acc2.x = fmaf(a2.comp, B.x, acc2.x); acc2.y = fmaf(a2.comp, B.y, acc2.y);     \
        acc2.z = fmaf(a2.comp, B.z, acc2.z); acc2.w = fmaf(a2.comp, B.w, acc2.w);     \
        acc3.x = fmaf(a3.comp, B.x, acc3.x); acc3.y = fmaf(a3.comp, B.y, acc3.y);     \
        acc3.z = fmaf(a3.comp, B.z, acc3.z); acc3.w = fmaf(a3.comp, B.w, acc3.w);
        DK(x, b0) DK(y, b1) DK(z, b2) DK(w, b3)
#undef DK
    }

    float4 bv = *(const float4*)&bias[tc];
    float4 wr = *(const float4*)&Wr0[tc];
    float4 accs[4] = {acc0, acc1, acc2, acc3};
    float part[4];
#pragma unroll
    for (int i = 0; i < 4; ++i) {
        float4 v = accs[i];
        v.x = fmaxf(v.x + bv.x, 0.f); v.y = fmaxf(v.y + bv.y, 0.f);
        v.z = fmaxf(v.z + bv.z, 0.f); v.w = fmaxf(v.w + bv.w, 0.f);
        int gr = r0 + tr + i;
        if (gr < n) *(float4*)&C[(size_t)gr * 64 + tc] = v;
        part[i] = v.x * wr.x + v.y * wr.y + v.z * wr.z + v.w * wr.w;
    }
#pragma unroll
    for (int off = 8; off > 0; off >>= 1) {
#pragma unroll
        for (int i = 0; i < 4; ++i) part[i] += __shfl_down(part[i], off);
    }
    if ((tid & 15) == 0) {
        float W0 = w0[0];
        float CONST = W0 * br0[0] + w1[0] * br1[0] + w2[0] * br2[0] + w3[0] * c3[0];
#pragma unroll
        for (int i = 0; i < 4; ++i) {
            int gr = r0 + tr + i;
            if (gr < n) outacc[gr] = W0 * part[i] + CONST;
        }
    }
}

// ================= mm64b: Y16[:, coff:coff+64] = A @ W (bf16 out, row stride 128) =================
template <int K>
__global__ __launch_bounds__(256) void mm64b(const float* __restrict__ A, const float* __restrict__ W,
                                             u16* __restrict__ Y16, int coff, int n) {
    __shared__ float As[64][68];
    __shared__ float Ws[K][68];
    const int tid = threadIdx.x;
    const int r0 = blockIdx.x * 64;

    for (int idx = tid; idx < K * 16; idx += 256) {
        int k = idx >> 4, cq = (idx & 15) * 4;
        *(float4*)&Ws[k][cq] = *(const float4*)&W[k * 64 + cq];
    }

    const int tr = (tid >> 4) * 4;
    const int tc = (tid & 15) * 4;
    float4 acc0 = {0,0,0,0}, acc1 = {0,0,0,0}, acc2 = {0,0,0,0}, acc3 = {0,0,0,0};

    for (int kb = 0; kb < K; kb += 64) {
        __syncthreads();
#pragma unroll
        for (int it = 0; it < 4; ++it) {
            int r = (tid >> 4) + it * 16;
            int cq = (tid & 15) * 4;
            int gr = r0 + r;
            float4 v = {0,0,0,0};
            if (gr < n) v = *(const float4*)&A[(size_t)gr * K + kb + cq];
            *(float4*)&As[r][cq] = v;
        }
        __syncthreads();
#pragma unroll
        for (int k = 0; k < 64; k += 4) {
            float4 a0 = *(const float4*)&As[tr + 0][k];
            float4 a1 = *(const float4*)&As[tr + 1][k];
            float4 a2 = *(const float4*)&As[tr + 2][k];
            float4 a3 = *(const float4*)&As[tr + 3][k];
            float4 b0 = *(const float4*)&Ws[kb + k + 0][tc];
            float4 b1 = *(const float4*)&Ws[kb + k + 1][tc];
            float4 b2 = *(const float4*)&Ws[kb + k + 2][tc];
            float4 b3 = *(const float4*)&Ws[kb + k + 3][tc];
#define DK(comp, B)                                                                   \
            acc0.x = fmaf(a0.comp, B.x, acc0.x); acc0.y = fmaf(a0.comp, B.y, acc0.y); \
            acc0.z = fmaf(a0.comp, B.z, acc0.z); acc0.w = fmaf(a0.comp, B.w, acc0.w); \
            acc1.x = fmaf(a1.comp, B.x, acc1.x); acc1.y = fmaf(a1.comp, B.y, acc1.y); \
            acc1.z = fmaf(a1.comp, B.z, acc1.z); acc1.w = fmaf(a1.comp, B.w, acc1.w); \
            acc2.x = fmaf(a2.comp, B.x, acc2.x); acc2.y = fmaf(a2.comp, B.y, acc2.y); \
            acc2.z = fmaf(a2.comp, B.z, acc2.z); acc2.w = fmaf(a2.comp, B.w, acc2.w); \
            acc3.x = fmaf(a3.comp, B.x, acc3.x); acc3.y = fmaf(a3.comp, B.y, acc3.y); \
            acc3.z = fmaf(a3.comp, B.z, acc3.z); acc3.w = fmaf(a3.comp, B.w, acc3.w);
            DK(x, b0) DK(y, b1) DK(z, b2) DK(w, b3)
#undef DK
        }
    }

    float4 accs[4] = {acc0, acc1, acc2, acc3};
#pragma unroll
    for (int i = 0; i < 4; ++i) {
        int gr = r0 + tr + i;
        if (gr < n) {
            ushort4 o;
            o.x = f2b(accs[i].x); o.y = f2b(accs[i].y); o.z = f2b(accs[i].z); o.w = f2b(accs[i].w);
            *(ushort4*)&Y16[(size_t)gr * 128 + coff + tc] = o;
        }
    }
}

// ================= gather + fused readout (+ optional z-projection, optional dest store) ==========
// wave = (dest, set); QUARTER-waves (16 lanes) each process one edge, lane = 4 channels via 2x u32.
// 4 edges per step, 8-edge unroll => 8 concurrent 8B loads per wave.
template <bool STORE, bool ZCOMP>
__global__ __launch_bounds__(256) void gatherRO(const int* __restrict__ starts,
                                                const int2* __restrict__ csr,
                                                const u16* __restrict__ Y16,
                                                const float* __restrict__ bA,
                                                const float* __restrict__ bB,
                                                float* __restrict__ dest,
                                                const float* __restrict__ Wr,
                                                const float* __restrict__ wl,
                                                const float* __restrict__ u31,
                                                const float* __restrict__ u32v,
                                                const float* __restrict__ w3,
                                                float* __restrict__ z1,
                                                float* __restrict__ z2,
                                                float* __restrict__ outacc, int N) {
    int wave = (blockIdx.x * blockDim.x + threadIdx.x) >> 6;
    int lane = threadIdx.x & 63;
    if (wave >= 2 * N) return;
    int set2 = wave >= N;
    int d = set2 ? wave - N : wave;
    int base = set2 ? N : 0;
    int yoff = set2 ? 64 : 0;
    int q = lane >> 4;          // quarter 0..3
    int m = lane & 15;          // channel-quad index: channels 4m..4m+3

    int s0 = __builtin_amdgcn_readfirstlane(starts[base + d]);
    int s1 = __builtin_amdgcn_readfirstlane(starts[base + d + 1]);

    float a0 = 0.f, a1 = 0.f, a2 = 0.f, a3 = 0.f;
    int j = s0;
    for (; j + 8 <= s1; j += 8) {
        int2 e0 = csr[j + q];
        int2 e1 = csr[j + 4 + q];
        uint2 ya = *(const uint2*)&Y16[(size_t)e0.x * 128 + yoff + 4 * m];
        uint2 yb = *(const uint2*)&Y16[(size_t)e1.x * 128 + yoff + 4 * m];
        float w0 = __int_as_float(e0.y), w1 = __int_as_float(e1.y);
        a0 = fmaf(w0, b2f((u16)ya.x), a0); a1 = fmaf(w0, b2f((u16)(ya.x >> 16)), a1);
        a2 = fmaf(w0, b2f((u16)ya.y), a2); a3 = fmaf(w0, b2f((u16)(ya.y >> 16)), a3);
        a0 = fmaf(w1, b2f((u16)yb.x), a0); a1 = fmaf(w1, b2f((u16)(yb.x >> 16)), a1);
        a2 = fmaf(w1, b2f((u16)yb.y), a2); a3 = fmaf(w1, b2f((u16)(yb.y >> 16)), a3);
    }
    if (j + 4 <= s1) {
        int2 e = csr[j + q];
        uint2 y = *(const uint2*)&Y16[(size_t)e.x * 128 + yoff + 4 * m];
        float w = __int_as_float(e.y);
        a0 = fmaf(w, b2f((u16)y.x), a0); a1 = fmaf(w, b2f((u16)(y.x >> 16)), a1);
        a2 = fmaf(w, b2f((u16)y.y), a2); a3 = fmaf(w, b2f((u16)(y.y >> 16)), a3);
        j += 4;
    }
    if (j + q < s1) {           // tail: up to 3 edges, quarters q >= remainder idle
        int2 e = csr[j + q];
        uint2 y = *(const uint2*)&Y16[(size_t)e.x * 128 + yoff + 4 * m];
        float w = __int_as_float(e.y);
        a0 = fmaf(w, b2f((u16)y.x), a0); a1 = fmaf(w, b2f((u16)(y.x >> 16)), a1);
        a2 = fmaf(w, b2f((u16)y.y), a2); a3 = fmaf(w, b2f((u16)(y.y >> 16)), a3);
    }
    // reduce across quarters (channels aligned: lane m of each quarter = channels 4m..4m+3)
    a0 += __shfl_down(a0, 32); a1 += __shfl_down(a1, 32);
    a2 += __shfl_down(a2, 32); a3 += __shfl_down(a3, 32);
    a0 += __shfl_down(a0, 16); a1 += __shfl_down(a1, 16);
    a2 += __shfl_down(a2, 16); a3 += __shfl_down(a3, 16);

    if (q == 0) {
        float4 bv = *(const float4*)&(set2 ? bB : bA)[4 * m];
        float v0 = a0 + bv.x, v1 = a1 + bv.y, v2 = a2 + bv.z, v3 = a3 + bv.w;
        if (STORE) {
            float4 o = {v0, v1, v2, v3};
            *(float4*)&dest[(size_t)d * 128 + yoff + 4 * m] = o;
        }
        float4 wr = *(const float4*)&Wr[yoff + 4 * m];
        float p = v0 * wr.x + v1 * wr.y + v2 * wr.z + v3 * wr.w;
        float p1 = 0.f, p2 = 0.f;
        if (ZCOMP) {
            float4 ua = *(const float4*)&u31[yoff + 4 * m];
            float4 ub = *(const float4*)&u32v[yoff + 4 * m];
            p1 = v0 * ua.x + v1 * ua.y + v2 * ua.z + v3 * ua.w;
            p2 = v0 * ub.x + v1 * ub.y + v2 * ub.z + v3 * ub.w;
        }
#pragma unroll
        for (int off = 8; off > 0; off >>= 1) {
            p += __shfl_down(p, off);
            if (ZCOMP) { p1 += __shfl_down(p1, off); p2 += __shfl_down(p2, off); }
        }
        if (m == 0) {
            atomicAdd(&outacc[d], wl[0] * p);
            if (ZCOMP) {
                float W3 = w3[0];
                atomicAdd(&z1[d], W3 * p1);
                atomicAdd(&z2[d], W3 * p2);
            }
        }
    }
}

// ================= gather3: out[d] = outacc[d] + sum_e1 wt*z1[src] + sum_e2 wt*z2[src] ============
__global__ __launch_bounds__(256) void gather3(const int* __restrict__ starts,
                                               const int2* __restrict__ csr,
                                               const float* __restrict__ z1,
                                               const float* __restrict__ z2,
                                               const float* __restrict__ outacc,
                                               float* __restrict__ out, int N) {
    int d = (blockIdx.x * blockDim.x + threadIdx.x) >> 6;
    int lane = threadIdx.x & 63;
    if (d >= N) return;
    int a0 = __builtin_amdgcn_readfirstlane(starts[d]);
    int a1 = __builtin_amdgcn_readfirstlane(starts[d + 1]);
    int b0 = __builtin_amdgcn_readfirstlane(starts[N + d]);
    int b1 = __builtin_amdgcn_readfirstlane(starts[N + d + 1]);
    float acc = 0.f;
    for (int j = a0 + lane; j < a1; j += 64) {
        int2 e = csr[j];
        acc = fmaf(__int_as_float(e.y), z1[e.x], acc);
    }
    for (int j = b0 + lane; j < b1; j += 64) {
        int2 e = csr[j];
        acc = fmaf(__int_as_float(e.y), z2[e.x], acc);
    }
#pragma unroll
    for (int off = 32; off > 0; off >>= 1) acc += __shfl_down(acc, off);
    if (lane == 0) out[d] = outacc[d] + acc;
}

// ================= host =================
static inline char* carve(char*& p, size_t bytes) {
    char* r = p;
    p += (bytes + 255) & ~(size_t)255;
    return r;
}

extern "C" void kernel_launch(void* const* d_in, const int* in_sizes, int n_in,
                              void* d_out, int out_size, void* d_ws, size_t ws_size,
                              hipStream_t stream) {
    const float* x    = (const float*)d_in[0];
    const int*   ei1  = (const int*)d_in[1];
    const int*   ei2  = (const int*)d_in[2];
    const float* W_in = (const float*)d_in[3];  const float* b_in = (const float*)d_in[4];
    const float* W11  = (const float*)d_in[5];
    const float* b11  = (const float*)d_in[6];
    const float* W12  = (const float*)d_in[7];  const float* b12  = (const float*)d_in[8];
    const float* W21  = (const float*)d_in[9];  const float* b21  = (const float*)d_in[10];
    const float* W22  = (const float*)d_in[11]; const float* b22  = (const float*)d_in[12];
    const float* W31  = (const float*)d_in[13]; const float* b31  = (const float*)d_in[14];
    const float* W32  = (const float*)d_in[15]; const float* b32  = (const float*)d_in[16];
    const float* Wr0  = (const float*)d_in[17]; const float* br0  = (const float*)d_in[18];
    const float* Wr1  = (const float*)d_in[19]; const float* br1  = (const float*)d_in[20];
    const float* Wr2  = (const float*)d_in[21]; const float* br2  = (const float*)d_in[22];
    const float* Wr3  = (const float*)d_in[23]; const float* br3  = (const float*)d_in[24];
    const float* w0   = (const float*)d_in[25];
    const float* w1   = (const float*)d_in[26];
    const float* w2   = (const float*)d_in[27];
    const float* w3   = (const float*)d_in[28];

    const int N  = in_sizes[0] / 64;   // 50000
    const int E1 = in_sizes[1] / 2;    // 800000
    const int E2 = in_sizes[2] / 2;
    const int N2 = 2 * N;

    char* p = (char*)d_ws;
    float* dinv1   = (float*)carve(p, (size_t)N * 4);
    float* dinv2   = (float*)carve(p, (size_t)N * 4);
    int*   degc    = (int*)  carve(p, (size_t)N2 * 4);
    int*   starts  = (int*)  carve(p, ((size_t)N2 + 1) * 4);
    int*   partial = (int*)  carve(p, 512 * 4);
    float* uws     = (float*)carve(p, (128 + 128 + 1) * 4);  // u31, u32, c3
    float* z       = (float*)carve(p, (size_t)N2 * 4);       // z1 | z2 contiguous
    int2*  csr     = (int2*) carve(p, (size_t)(E1 + E2) * 8);
    float* R0      = (float*)carve(p, (size_t)N * 64 * 4);
    float* P       = (float*)carve(p, (size_t)N * 128 * 4);
    u16*   Y16     = (u16*)  carve(p, (size_t)N * 128 * 2);
    float* outacc  = (float*)carve(p, (size_t)N * 4);
    float* u31 = uws, *u32v = uws + 128, *c3 = uws + 256;
    float* z1 = z, *z2 = z + N;
    (void)ws_size; (void)n_in; (void)out_size;

    const int B = 256;
    dim3 blk(B);
    int gN   = (N + B - 1) / B;
    int gE   = (E1 + E2 + B - 1) / B;
    int gMM  = (N + 63) / 64;
    int gGa  = (int)(((long long)N2 * 64 + B - 1) / B);
    int gG3  = (int)(((long long)N * 64 + B - 1) / B);
    int nb   = (N2 + 255) / 256;

    // ---- CSR build + u-precompute ----
    hipMemsetAsync(degc, 0, (size_t)N2 * 4, stream);
    hipMemsetAsync(z, 0, (size_t)N2 * 4, stream);
    uprep<<<1, 128, 0, stream>>>(W31, W32, b31, b32, Wr3, br3, u31, u32v, c3);
    degcnt_all<<<gE, blk, 0, stream>>>(ei1 + E1, ei2 + E2, degc, N, E1, E2);
    dinv_fin<<<gN, blk, 0, stream>>>(degc, dinv1, dinv2, N);
    scan1<<<nb, blk, 0, stream>>>(degc, partial, N2);
    scan2<<<1, 512, 0, stream>>>(partial, nb, starts, N2);
    scan3<<<nb, blk, 0, stream>>>(degc, partial, starts, N2);
    // 4 dest-range passes: live CSR write region ~3.2 MB/pass stays L2-resident
    const int NPASS = 4;
    for (int ps = 0; ps < NPASS; ++ps) {
        int lo = (int)((long long)N * ps / NPASS);
        int hi = (int)((long long)N * (ps + 1) / NPASS);
        csr_fill_pass<<<gE, blk, 0, stream>>>(ei1, ei2, dinv1, dinv2, starts, degc, csr,
                                              N, E1, E2, lo, hi);
    }

    // ---- R0 = relu(x @ W_in + b_in); outacc = w0*readout0 + CONST ----
    mm_in<<<gMM, blk, 0, stream>>>(x, W_in, b_in, R0, Wr0, br0, br1, br2,
                                   w0, w1, w2, w3, c3, outacc, N);

    // ---- layer 1: P = R1; readout1 fused ----
    mm64b<64><<<gMM, blk, 0, stream>>>(R0, W11, Y16, 0, N);
    mm64b<64><<<gMM, blk, 0, stream>>>(R0, W12, Y16, 64, N);
    gatherRO<true, false><<<gGa, blk, 0, stream>>>(starts, csr, Y16, b11, b12, P, Wr1, w1,
                                                   u31, u32v, w3, z1, z2, outacc, N);

    // ---- layer 2: Q never materialized; readout2 + z-projection fused ----
    mm64b<128><<<gMM, blk, 0, stream>>>(P, W21, Y16, 0, N);
    mm64b<128><<<gMM, blk, 0, stream>>>(P, W22, Y16, 64, N);
    gatherRO<false, true><<<gGa, blk, 0, stream>>>(starts, csr, Y16, b21, b22, nullptr, Wr2, w2,
                                                   u31, u32v, w3, z1, z2, outacc, N);

    // ---- layer 3 (algebraic shortcut): out = outacc + gather(z) ----
    gather3<<<gG3, blk, 0, stream>>>(starts, csr, z1, z2, outacc, (float*)d_out, N);
}

// Round 9
// 478.184 us; speedup vs baseline: 1.1223x; 1.1223x over previous
//
#include <hip/hip_runtime.h>
#include <cstdint>
#include <cstddef>

typedef unsigned short u16;
typedef unsigned int u32;
typedef __attribute__((ext_vector_type(8))) short shortx8;
typedef __attribute__((ext_vector_type(4))) float floatx4;

__device__ __forceinline__ u16 f2b(float f) {
    u32 b = __float_as_uint(f);
    b += 0x7fffu + ((b >> 16) & 1u);   // RNE
    return (u16)(b >> 16);
}
__device__ __forceinline__ float b2f(u16 u) {
    return __uint_as_float(((u32)u) << 16);
}

// ================= u-precompute: u31 = W31@Wr3[0:64], u32 = W32@Wr3[64:128], c3 =================
__global__ void uprep(const float* __restrict__ W31, const float* __restrict__ W32,
                      const float* __restrict__ b31, const float* __restrict__ b32,
                      const float* __restrict__ Wr3, const float* __restrict__ br3,
                      float* __restrict__ u31, float* __restrict__ u32, float* __restrict__ c3) {
    __shared__ float s[64];
    int t = threadIdx.x;
    if (t < 128) {
        float a = 0.f, b = 0.f;
        for (int c = 0; c < 64; ++c) {
            a = fmaf(W31[t * 64 + c], Wr3[c], a);
            b = fmaf(W32[t * 64 + c], Wr3[64 + c], b);
        }
        u31[t] = a;
        u32[t] = b;
    }
    if (t < 64) s[t] = b31[t] * Wr3[t] + b32[t] * Wr3[64 + t];
    __syncthreads();
    if (t < 32) s[t] += s[t + 32];
    __syncthreads();
    if (t == 0) {
        float acc = 0.f;
        for (int i = 0; i < 32; ++i) acc += s[i];
        c3[0] = acc + br3[0];
    }
}

// ================= CSR build (split-4 sub-counters: contention /4) =================
__global__ void degcnt_all(const int* __restrict__ c1, const int* __restrict__ c2,
                           int* __restrict__ degc4, int N, int E1, int E2) {
    int e = blockIdx.x * blockDim.x + threadIdx.x;
    if (e < E1) atomicAdd(&degc4[4 * c1[e] + (e & 3)], 1);
    else if (e < E1 + E2) {
        int t = e - E1;
        atomicAdd(&degc4[4 * (N + c2[t]) + (t & 3)], 1);
    }
}

__global__ void dinv_fin(const int* __restrict__ degc4, float* __restrict__ d1,
                         float* __restrict__ d2, int n) {
    int i = blockIdx.x * blockDim.x + threadIdx.x;
    if (i < n) {
        int a = degc4[4*i] + degc4[4*i+1] + degc4[4*i+2] + degc4[4*i+3];
        int j = n + i;
        int b = degc4[4*j] + degc4[4*j+1] + degc4[4*j+2] + degc4[4*j+3];
        d1[i] = a > 0 ? rsqrtf((float)a) : 0.f;
        d2[i] = b > 0 ? rsqrtf((float)b) : 0.f;
    }
}

__global__ void scan1(const int* __restrict__ deg, int* __restrict__ partial, int n) {
    __shared__ int s[256];
    int i = blockIdx.x * 256 + threadIdx.x;
    s[threadIdx.x] = (i < n) ? deg[i] : 0;
    __syncthreads();
    for (int off = 128; off > 0; off >>= 1) {
        if (threadIdx.x < off) s[threadIdx.x] += s[threadIdx.x + off];
        __syncthreads();
    }
    if (threadIdx.x == 0) partial[blockIdx.x] = s[0];
}

// single-block sequential-chunk exclusive scan over nb partials (carry loop)
__global__ void scan2(int* __restrict__ partial, int nb, int* __restrict__ starts, int n) {
    __shared__ int s[256];
    __shared__ int carry;
    int t = threadIdx.x;
    if (t == 0) carry = 0;
    __syncthreads();
    for (int c0 = 0; c0 < nb; c0 += 256) {
        int i = c0 + t;
        int v = (i < nb) ? partial[i] : 0;
        s[t] = v;
        __syncthreads();
        for (int off = 1; off < 256; off <<= 1) {
            int u = (t >= off) ? s[t - off] : 0;
            __syncthreads();
            s[t] += u;
            __syncthreads();
        }
        if (i < nb) partial[i] = carry + s[t] - v;   // exclusive
        __syncthreads();
        if (t == 255) carry += s[255];
        __syncthreads();
    }
    if (t == 0) starts[n] = carry;
}

__global__ void scan3(const int* __restrict__ deg, const int* __restrict__ partial,
                      int* __restrict__ starts, int n) {
    __shared__ int s[256];
    int i = blockIdx.x * 256 + threadIdx.x;
    int v = (i < n) ? deg[i] : 0;
    s[threadIdx.x] = v;
    __syncthreads();
    for (int off = 1; off < 256; off <<= 1) {
        int u = (threadIdx.x >= off) ? s[threadIdx.x - off] : 0;
        __syncthreads();
        s[threadIdx.x] += u;
        __syncthreads();
    }
    if (i < n) starts[i] = partial[blockIdx.x] + s[threadIdx.x] - v;
}

// fill CSR slots for dests in [lo,hi) only — live write region stays L2-resident.
// degc4 reused as countdown cursors (split by edge&3: contention /4).
__global__ void csr_fill_pass(const int* __restrict__ ei1, const int* __restrict__ ei2,
                              const float* __restrict__ dinv1, const float* __restrict__ dinv2,
                              const int* __restrict__ starts4, int* __restrict__ degc4,
                              int2* __restrict__ csr, int N, int E1, int E2, int lo, int hi) {
    int e = blockIdx.x * blockDim.x + threadIdx.x;
    int c, base, idx;
    const int* rows;
    const float* dinv;
    if (e < E1) { c = ei1[E1 + e]; base = 0; rows = ei1; dinv = dinv1; idx = e; }
    else if (e < E1 + E2) { int t = e - E1; c = ei2[E2 + t]; base = N; rows = ei2; dinv = dinv2; idx = t; }
    else return;
    if (c < lo || c >= hi) return;
    int r = rows[idx];
    int slot = 4 * (base + c) + (idx & 3);
    int pos = starts4[slot] + atomicSub(&degc4[slot], 1) - 1;
    csr[pos] = make_int2(r, __float_as_int(dinv[r] * dinv[c]));
}

// ================= mm_in: R0 = relu(x@W_in + b_in); fused readout0 + outacc init (fp32) ==========
__global__ __launch_bounds__(256) void mm_in(const float* __restrict__ A, const float* __restrict__ W,
                                             const float* __restrict__ bias, float* __restrict__ C,
                                             const float* __restrict__ Wr0, const float* __restrict__ br0,
                                             const float* __restrict__ br1, const float* __restrict__ br2,
                                             const float* __restrict__ w0, const float* __restrict__ w1,
                                             const float* __restrict__ w2, const float* __restrict__ w3,
                                             const float* __restrict__ c3, float* __restrict__ outacc,
                                             int n) {
    __shared__ float As[64][68];
    __shared__ float Ws[64][68];
    const int tid = threadIdx.x;
    const int r0 = blockIdx.x * 64;

    for (int idx = tid; idx < 64 * 16; idx += 256) {
        int k = idx >> 4, cq = (idx & 15) * 4;
        *(float4*)&Ws[k][cq] = *(const float4*)&W[k * 64 + cq];
    }

    const int tr = (tid >> 4) * 4;
    const int tc = (tid & 15) * 4;
    float4 acc0 = {0,0,0,0}, acc1 = {0,0,0,0}, acc2 = {0,0,0,0}, acc3 = {0,0,0,0};

    __syncthreads();
#pragma unroll
    for (int it = 0; it < 4; ++it) {
        int r = (tid >> 4) + it * 16;
        int cq = (tid & 15) * 4;
        int gr = r0 + r;
        float4 v = {0,0,0,0};
        if (gr < n) v = *(const float4*)&A[(size_t)gr * 64 + cq];
        *(float4*)&As[r][cq] = v;
    }
    __syncthreads();
#pragma unroll
    for (int k = 0; k < 64; k += 4) {
        float4 a0 = *(const float4*)&As[tr + 0][k];
        float4 a1 = *(const float4*)&As[tr + 1][k];
        float4 a2 = *(const float4*)&As[tr + 2][k];
        float4 a3 = *(const float4*)&As[tr + 3][k];
        float4 b0 = *(const float4*)&Ws[k + 0][tc];
        float4 b1 = *(const float4*)&Ws[k + 1][tc];
        float4 b2 = *(const float4*)&Ws[k + 2][tc];
        float4 b3 = *(const float4*)&Ws[k + 3][tc];
#define DK(comp, B)                                                                   \
        acc0.x = fmaf(a0.comp, B.x, acc0.x); acc0.y = fmaf(a0.comp, B.y, acc0.y);     \
        acc0.z = fmaf(a0.comp, B.z, acc0.z); acc0.w = fmaf(a0.comp, B.w, acc0.w);     \
        acc1.x = fmaf(a1.comp, B.x, acc1.x); acc1.y = fmaf(a1.comp, B.y, acc1.y);     \
        acc1.z = fmaf(a1.comp, B.z, acc1.z); acc1.w = fmaf(a1.comp, B.w, acc1.w);     \
        acc2.x = fmaf(a2.comp, B.x, acc2.x); acc2.y = fmaf(a2.comp, B.y, acc2.y);     \
        acc2.z = fmaf(a2.comp, B.z, acc2.z); acc2.w = fmaf(a2.comp, B.w, acc2.w);     \
        acc3.x = fmaf(a3.comp, B.x, acc3.x); acc3.y = fmaf(a3.comp, B.y, acc3.y);     \
        acc3.z = fmaf(a3.comp, B.z, acc3.z); acc3.w = fmaf(a3.comp, B.w, acc3.w);
        DK(x, b0) DK(y, b1) DK(z, b2) DK(w, b3)
#undef DK
    }

    float4 bv = *(const float4*)&bias[tc];
    float4 wr = *(const float4*)&Wr0[tc];
    float4 accs[4] = {acc0, acc1, acc2, acc3};
    float part[4];
#pragma unroll
    for (int i = 0; i < 4; ++i) {
        float4 v = accs[i];
        v.x = fmaxf(v.x + bv.x, 0.f); v.y = fmaxf(v.y + bv.y, 0.f);
        v.z = fmaxf(v.z + bv.z, 0.f); v.w = fmaxf(v.w + bv.w, 0.f);
        int gr = r0 + tr + i;
        if (gr < n) *(float4*)&C[(size_t)gr * 64 + tc] = v;
        part[i] = v.x * wr.x + v.y * wr.y + v.z * wr.z + v.w * wr.w;
    }
#pragma unroll
    for (int off = 8; off > 0; off >>= 1) {
#pragma unroll
        for (int i = 0; i < 4; ++i) part[i] += __shfl_down(part[i], off);
    }
    if ((tid & 15) == 0) {
        float W0 = w0[0];
        float CONST = W0 * br0[0] + w1[0] * br1[0] + w2[0] * br2[0] + w3[0] * c3[0];
#pragma unroll
        for (int i = 0; i < 4; ++i) {
            int gr = r0 + tr + i;
            if (gr < n) outacc[gr] = W0 * part[i] + CONST;
        }
    }
}

// ================= mmfma: Y16[:, coff:coff+64] = bf16(A) @ bf16(W) via MFMA 16x16x32 ==============
// block = 256 = 4 waves; wave w: rows 16w..16w+15, all 64 cols (4 n-tiles).
template <int K>
__global__ __launch_bounds__(256) void mmfma(const float* __restrict__ A, const float* __restrict__ W,
                                             u16* __restrict__ Y16, int coff, int n) {
    constexpr int LDA = K + 8;            // bf16 elems/row; row stride = 2*LDA B (16B-aligned, 2-way banks)
    __shared__ u16 As[64 * LDA];
    __shared__ u16 Wt[64 * LDA];          // Wt[n][k]  (W transposed)
    const int tid = threadIdx.x;
    const int r0 = blockIdx.x * 64;

    // stage A tile (fp32 -> bf16), coalesced
    for (int idx = tid; idx < 16 * K; idx += 256) {
        int r = idx / (K / 4);
        int qc = idx % (K / 4);
        int gr = r0 + r;
        float4 v = {0,0,0,0};
        if (gr < n) v = *(const float4*)&A[(size_t)gr * K + 4 * qc];
        ushort4 o = {f2b(v.x), f2b(v.y), f2b(v.z), f2b(v.w)};
        *(ushort4*)&As[r * LDA + 4 * qc] = o;
    }
    // stage W transposed (fp32 -> bf16)
    for (int idx = tid; idx < 16 * K; idx += 256) {
        int k = idx >> 4;
        int qc = idx & 15;
        float4 v = *(const float4*)&W[k * 64 + 4 * qc];
        Wt[(4*qc+0) * LDA + k] = f2b(v.x);
        Wt[(4*qc+1) * LDA + k] = f2b(v.y);
        Wt[(4*qc+2) * LDA + k] = f2b(v.z);
        Wt[(4*qc+3) * LDA + k] = f2b(v.w);
    }
    __syncthreads();

    const int wave = tid >> 6;
    const int lane = tid & 63;
    const int m = lane & 15;              // row-in-tile (A) / col-in-tile (B)
    const int ko = (lane >> 4) * 8;       // k-offset within 32-chunk
    floatx4 z4 = {0.f, 0.f, 0.f, 0.f};
    floatx4 acc[4] = {z4, z4, z4, z4};

#pragma unroll
    for (int kc = 0; kc < K; kc += 32) {
        shortx8 af = *(shortx8*)&As[(wave * 16 + m) * LDA + kc + ko];
#pragma unroll
        for (int nt = 0; nt < 4; ++nt) {
            shortx8 bf = *(shortx8*)&Wt[(nt * 16 + m) * LDA + kc + ko];
            acc[nt] = __builtin_amdgcn_mfma_f32_16x16x32_bf16(af, bf, acc[nt], 0, 0, 0);
        }
    }

    // C/D layout: col = lane&15, row = (lane>>4)*4 + reg
    const int rbase = r0 + wave * 16 + (lane >> 4) * 4;
#pragma unroll
    for (int nt = 0; nt < 4; ++nt) {
#pragma unroll
        for (int rg = 0; rg < 4; ++rg) {
            int gr = rbase + rg;
            if (gr < n) Y16[(size_t)gr * 128 + coff + nt * 16 + m] = f2b(acc[nt][rg]);
        }
    }
}

// ================= gather + fused readout (+ optional z-projection, optional dest store) ==========
// wave = (dest, set); QUARTER-waves (16 lanes) each process one edge, lane = 4 channels.
template <bool STORE, bool ZCOMP>
__global__ __launch_bounds__(256) void gatherRO(const int* __restrict__ starts4,
                                                const int2* __restrict__ csr,
                                                const u16* __restrict__ Y16,
                                                const float* __restrict__ bA,
                                                const float* __restrict__ bB,
                                                float* __restrict__ dest,
                                                const float* __restrict__ Wr,
                                                const float* __restrict__ wl,
                                                const float* __restrict__ u31,
                                                const float* __restrict__ u32v,
                                                const float* __restrict__ w3,
                                                float* __restrict__ z1,
                                                float* __restrict__ z2,
                                                float* __restrict__ outacc, int N) {
    int wave = (blockIdx.x * blockDim.x + threadIdx.x) >> 6;
    int lane = threadIdx.x & 63;
    if (wave >= 2 * N) return;
    int set2 = wave >= N;
    int d = set2 ? wave - N : wave;
    int base = set2 ? N : 0;
    int yoff = set2 ? 64 : 0;
    int q = lane >> 4;
    int m = lane & 15;

    int s0 = __builtin_amdgcn_readfirstlane(starts4[(base + d) * 4]);
    int s1 = __builtin_amdgcn_readfirstlane(starts4[(base + d) * 4 + 4]);

    float a0 = 0.f, a1 = 0.f, a2 = 0.f, a3 = 0.f;
    int j = s0;
    for (; j + 8 <= s1; j += 8) {
        int2 e0 = csr[j + q];
        int2 e1 = csr[j + 4 + q];
        uint2 ya = *(const uint2*)&Y16[(size_t)e0.x * 128 + yoff + 4 * m];
        uint2 yb = *(const uint2*)&Y16[(size_t)e1.x * 128 + yoff + 4 * m];
        float w0 = __int_as_float(e0.y), w1 = __int_as_float(e1.y);
        a0 = fmaf(w0, b2f((u16)ya.x), a0); a1 = fmaf(w0, b2f((u16)(ya.x >> 16)), a1);
        a2 = fmaf(w0, b2f((u16)ya.y), a2); a3 = fmaf(w0, b2f((u16)(ya.y >> 16)), a3);
        a0 = fmaf(w1, b2f((u16)yb.x), a0); a1 = fmaf(w1, b2f((u16)(yb.x >> 16)), a1);
        a2 = fmaf(w1, b2f((u16)yb.y), a2); a3 = fmaf(w1, b2f((u16)(yb.y >> 16)), a3);
    }
    if (j + 4 <= s1) {
        int2 e = csr[j + q];
        uint2 y = *(const uint2*)&Y16[(size_t)e.x * 128 + yoff + 4 * m];
        float w = __int_as_float(e.y);
        a0 = fmaf(w, b2f((u16)y.x), a0); a1 = fmaf(w, b2f((u16)(y.x >> 16)), a1);
        a2 = fmaf(w, b2f((u16)y.y), a2); a3 = fmaf(w, b2f((u16)(y.y >> 16)), a3);
        j += 4;
    }
    if (j + q < s1) {
        int2 e = csr[j + q];
        uint2 y = *(const uint2*)&Y16[(size_t)e.x * 128 + yoff + 4 * m];
        float w = __int_as_float(e.y);
        a0 = fmaf(w, b2f((u16)y.x), a0); a1 = fmaf(w, b2f((u16)(y.x >> 16)), a1);
        a2 = fmaf(w, b2f((u16)y.y), a2); a3 = fmaf(w, b2f((u16)(y.y >> 16)), a3);
    }
    a0 += __shfl_down(a0, 32); a1 += __shfl_down(a1, 32);
    a2 += __shfl_down(a2, 32); a3 += __shfl_down(a3, 32);
    a0 += __shfl_down(a0, 16); a1 += __shfl_down(a1, 16);
    a2 += __shfl_down(a2, 16); a3 += __shfl_down(a3, 16);

    if (q == 0) {
        float4 bv = *(const float4*)&(set2 ? bB : bA)[4 * m];
        float v0 = a0 + bv.x, v1 = a1 + bv.y, v2 = a2 + bv.z, v3 = a3 + bv.w;
        if (STORE) {
            float4 o = {v0, v1, v2, v3};
            *(float4*)&dest[(size_t)d * 128 + yoff + 4 * m] = o;
        }
        float4 wr = *(const float4*)&Wr[yoff + 4 * m];
        float p = v0 * wr.x + v1 * wr.y + v2 * wr.z + v3 * wr.w;
        float p1 = 0.f, p2 = 0.f;
        if (ZCOMP) {
            float4 ua = *(const float4*)&u31[yoff + 4 * m];
            float4 ub = *(const float4*)&u32v[yoff + 4 * m];
            p1 = v0 * ua.x + v1 * ua.y + v2 * ua.z + v3 * ua.w;
            p2 = v0 * ub.x + v1 * ub.y + v2 * ub.z + v3 * ub.w;
        }
#pragma unroll
        for (int off = 8; off > 0; off >>= 1) {
            p += __shfl_down(p, off);
            if (ZCOMP) { p1 += __shfl_down(p1, off); p2 += __shfl_down(p2, off); }
        }
        if (m == 0) {
            atomicAdd(&outacc[d], wl[0] * p);
            if (ZCOMP) {
                float W3 = w3[0];
                atomicAdd(&z1[d], W3 * p1);
                atomicAdd(&z2[d], W3 * p2);
            }
        }
    }
}

// ================= gather3: out[d] = outacc[d] + sum_e1 wt*z1[src] + sum_e2 wt*z2[src] ============
__global__ __launch_bounds__(256) void gather3(const int* __restrict__ starts4,
                                               const int2* __restrict__ csr,
                                               const float* __restrict__ z1,
                                               const float* __restrict__ z2,
                                               const float* __restrict__ outacc,
                                               float* __restrict__ out, int N) {
    int d = (blockIdx.x * blockDim.x + threadIdx.x) >> 6;
    int lane = threadIdx.x & 63;
    if (d >= N) return;
    int a0 = __builtin_amdgcn_readfirstlane(starts4[4 * d]);
    int a1 = __builtin_amdgcn_readfirstlane(starts4[4 * d + 4]);
    int b0 = __builtin_amdgcn_readfirstlane(starts4[4 * (N + d)]);
    int b1 = __builtin_amdgcn_readfirstlane(starts4[4 * (N + d) + 4]);
    float acc = 0.f;
    for (int j = a0 + lane; j < a1; j += 64) {
        int2 e = csr[j];
        acc = fmaf(__int_as_float(e.y), z1[e.x], acc);
    }
    for (int j = b0 + lane; j < b1; j += 64) {
        int2 e = csr[j];
        acc = fmaf(__int_as_float(e.y), z2[e.x], acc);
    }
#pragma unroll
    for (int off = 32; off > 0; off >>= 1) acc += __shfl_down(acc, off);
    if (lane == 0) out[d] = outacc[d] + acc;
}

// ================= host =================
static inline char* carve(char*& p, size_t bytes) {
    char* r = p;
    p += (bytes + 255) & ~(size_t)255;
    return r;
}

extern "C" void kernel_launch(void* const* d_in, const int* in_sizes, int n_in,
                              void* d_out, int out_size, void* d_ws, size_t ws_size,
                              hipStream_t stream) {
    const float* x    = (const float*)d_in[0];
    const int*   ei1  = (const int*)d_in[1];
    const int*   ei2  = (const int*)d_in[2];
    const float* W_in = (const float*)d_in[3];  const float* b_in = (const float*)d_in[4];
    const float* W11  = (const float*)d_in[5];
    const float* b11  = (const float*)d_in[6];
    const float* W12  = (const float*)d_in[7];  const float* b12  = (const float*)d_in[8];
    const float* W21  = (const float*)d_in[9];  const float* b21  = (const float*)d_in[10];
    const float* W22  = (const float*)d_in[11]; const float* b22  = (const float*)d_in[12];
    const float* W31  = (const float*)d_in[13]; const float* b31  = (const float*)d_in[14];
    const float* W32  = (const float*)d_in[15]; const float* b32  = (const float*)d_in[16];
    const float* Wr0  = (const float*)d_in[17]; const float* br0  = (const float*)d_in[18];
    const float* Wr1  = (const float*)d_in[19]; const float* br1  = (const float*)d_in[20];
    const float* Wr2  = (const float*)d_in[21]; const float* br2  = (const float*)d_in[22];
    const float* Wr3  = (const float*)d_in[23]; const float* br3  = (const float*)d_in[24];
    const float* w0   = (const float*)d_in[25];
    const float* w1   = (const float*)d_in[26];
    const float* w2   = (const float*)d_in[27];
    const float* w3   = (const float*)d_in[28];

    const int N  = in_sizes[0] / 64;   // 50000
    const int E1 = in_sizes[1] / 2;    // 800000
    const int E2 = in_sizes[2] / 2;
    const int N2 = 2 * N;
    const int N8 = 4 * N2;             // split-4 counter count

    char* p = (char*)d_ws;
    float* dinv1   = (float*)carve(p, (size_t)N * 4);
    float* dinv2   = (float*)carve(p, (size_t)N * 4);
    int*   degc4   = (int*)  carve(p, (size_t)N8 * 4);
    int*   starts4 = (int*)  carve(p, ((size_t)N8 + 1) * 4);
    int*   partial = (int*)  carve(p, 2048 * 4);
    float* uws     = (float*)carve(p, (128 + 128 + 1) * 4);  // u31, u32, c3
    float* z       = (float*)carve(p, (size_t)N2 * 4);       // z1 | z2
    int2*  csr     = (int2*) carve(p, (size_t)(E1 + E2) * 8);
    float* R0      = (float*)carve(p, (size_t)N * 64 * 4);
    float* P       = (float*)carve(p, (size_t)N * 128 * 4);
    u16*   Y16     = (u16*)  carve(p, (size_t)N * 128 * 2);
    float* outacc  = (float*)carve(p, (size_t)N * 4);
    float* u31 = uws, *u32v = uws + 128, *c3 = uws + 256;
    float* z1 = z, *z2 = z + N;
    (void)ws_size; (void)n_in; (void)out_size;

    const int B = 256;
    dim3 blk(B);
    int gN   = (N + B - 1) / B;
    int gE   = (E1 + E2 + B - 1) / B;
    int gMM  = (N + 63) / 64;
    int gGa  = (int)(((long long)N2 * 64 + B - 1) / B);
    int gG3  = (int)(((long long)N * 64 + B - 1) / B);
    int nb4  = (N8 + 255) / 256;

    // ---- CSR build + u-precompute ----
    hipMemsetAsync(degc4, 0, (size_t)N8 * 4, stream);
    hipMemsetAsync(z, 0, (size_t)N2 * 4, stream);
    uprep<<<1, 128, 0, stream>>>(W31, W32, b31, b32, Wr3, br3, u31, u32v, c3);
    degcnt_all<<<gE, blk, 0, stream>>>(ei1 + E1, ei2 + E2, degc4, N, E1, E2);
    dinv_fin<<<gN, blk, 0, stream>>>(degc4, dinv1, dinv2, N);
    scan1<<<nb4, blk, 0, stream>>>(degc4, partial, N8);
    scan2<<<1, 256, 0, stream>>>(partial, nb4, starts4, N8);
    scan3<<<nb4, blk, 0, stream>>>(degc4, partial, starts4, N8);
    const int NPASS = 4;
    for (int ps = 0; ps < NPASS; ++ps) {
        int lo = (int)((long long)N * ps / NPASS);
        int hi = (int)((long long)N * (ps + 1) / NPASS);
        csr_fill_pass<<<gE, blk, 0, stream>>>(ei1, ei2, dinv1, dinv2, starts4, degc4, csr,
                                              N, E1, E2, lo, hi);
    }

    // ---- R0 = relu(x @ W_in + b_in); outacc = w0*readout0 + CONST ----
    mm_in<<<gMM, blk, 0, stream>>>(x, W_in, b_in, R0, Wr0, br0, br1, br2,
                                   w0, w1, w2, w3, c3, outacc, N);

    // ---- layer 1: P = R1; readout1 fused ----
    mmfma<64><<<gMM, blk, 0, stream>>>(R0, W11, Y16, 0, N);
    mmfma<64><<<gMM, blk, 0, stream>>>(R0, W12, Y16, 64, N);
    gatherRO<true, false><<<gGa, blk, 0, stream>>>(starts4, csr, Y16, b11, b12, P, Wr1, w1,
                                                   u31, u32v, w3, z1, z2, outacc, N);

    // ---- layer 2: Q never materialized; readout2 + z-projection fused ----
    mmfma<128><<<gMM, blk, 0, stream>>>(P, W21, Y16, 0, N);
    mmfma<128><<<gMM, blk, 0, stream>>>(P, W22, Y16, 64, N);
    gatherRO<false, true><<<gGa, blk, 0, stream>>>(starts4, csr, Y16, b21, b22, nullptr, Wr2, w2,
                                                   u31, u32v, w3, z1, z2, outacc, N);

    // ---- layer 3 (algebraic shortcut): out = outacc + gather(z) ----
    gather3<<<gG3, blk, 0, stream>>>(starts4, csr, z1, z2, outacc, (float*)d_out, N);
}